// Round 17
// baseline (323.765 us; speedup 1.0000x reference)
//
#include <hip/hip_runtime.h>
#include <hip/hip_bf16.h>
#include <math.h>

// Problem constants: B=2, S=2048, E=2048, HEADS=16, d=128
#define PB 2
#define PS 2048
#define PE 2048
#define PH 16
#define PD 128
#define PN_PROJ 6160   // 3*E + HEADS (fp32 weight layout)
#define PM 4096        // B*S

typedef __attribute__((ext_vector_type(8))) short bf16x8;
typedef __attribute__((ext_vector_type(4))) float f32x4;

__device__ __forceinline__ void gload_lds16(const void* g, void* l) {
  __builtin_amdgcn_global_load_lds((const __attribute__((address_space(1))) void*)g,
                                   (__attribute__((address_space(3))) void*)l, 16, 0, 0);
}

// ---------------------------------------------------------------------------
// GEMM1: R9-exact cs2 schedule (proven 898 TF, 0 conflicts), 128x384 tile
// (BN=384 = exactly one head). Epilogue writes packed Qp/Kp[bh][s][d] and
// V TRANSPOSED directly into Vtp[bh][d][s].
// ---------------------------------------------------------------------------
__global__ __launch_bounds__(512, 1) void gemm_qkv(
    const __hip_bfloat16* __restrict__ A, const __hip_bfloat16* __restrict__ Bt,
    __hip_bfloat16* __restrict__ Qp, __hip_bfloat16* __restrict__ Kp,
    __hip_bfloat16* __restrict__ Vtp, int K, int nTilesX) {
  constexpr int BM = 128, BN = 384, WM = 2, WN = 4;
  constexpr int MF = BM / WM / 16;   // 4
  constexpr int NF = BN / WN / 16;   // 6
  constexpr int SLOT = (BM + BN) * 64;
  constexpr int AL = BM / 64;
  constexpr int BL = BN / 64;
  constexpr int NLD = AL + BL;

  __shared__ __align__(16) __hip_bfloat16 lds[2 * SLOT];

  const int tid = threadIdx.x;
  const int w = tid >> 6, lane = tid & 63;
  const int fq = lane >> 4, fr = lane & 15;
  const int wm = w / WN, wn = w % WN;

  const int total = gridDim.x;
  const int swz = (blockIdx.x & 7) * (total >> 3) + (blockIdx.x >> 3);
  const int mBase = (swz / nTilesX) * BM;
  const int h = swz % nTilesX;       // head (BN == 384 == one head)
  const int nBase = h * BN;

  const int srow = tid >> 3, sc = tid & 7;

  auto stage = [&](int t) {
    char* base = (char*)lds + (size_t)(t & 1) * SLOT * 2;
#pragma unroll
    for (int l = 0; l < AL; ++l) {
      int row = l * 64 + srow;
      int cs = sc ^ (row & 7);
      gload_lds16(A + (size_t)(mBase + row) * K + t * 64 + cs * 8,
                  base + l * 8192 + w * 1024);
    }
#pragma unroll
    for (int l = 0; l < BL; ++l) {
      int row = l * 64 + srow;
      int cs = sc ^ (row & 7);
      gload_lds16(Bt + (size_t)(nBase + row) * K + t * 64 + cs * 8,
                  base + BM * 128 + l * 8192 + w * 1024);
    }
  };

  f32x4 acc[MF][NF];
#pragma unroll
  for (int m = 0; m < MF; ++m)
#pragma unroll
    for (int n = 0; n < NF; ++n) acc[m][n] = (f32x4){0.f, 0.f, 0.f, 0.f};

  const int NT = K / 64;
  stage(0); stage(1);

#pragma unroll 1
  for (int t = 0; t < NT; ++t) {
    if (t + 1 < NT) asm volatile("s_waitcnt vmcnt(%0)" ::"i"(NLD) : "memory");
    else            asm volatile("s_waitcnt vmcnt(0)" ::: "memory");
    __builtin_amdgcn_s_barrier();
    __builtin_amdgcn_sched_barrier(0);

    const __hip_bfloat16* sl = lds + (size_t)(t & 1) * SLOT;

    // ---- kk = 0 ----
    bf16x8 av[MF], bv[NF];
#pragma unroll
    for (int m = 0; m < MF; ++m) {
      int row = wm * (BM / WM) + m * 16 + fr;
      av[m] = *(const bf16x8*)&sl[row * 64 + ((fq ^ (row & 7)) * 8)];
    }
#pragma unroll
    for (int n = 0; n < NF; ++n) {
      int row = wn * (BN / WN) + n * 16 + fr;
      bv[n] = *(const bf16x8*)&sl[BM * 64 + row * 64 + ((fq ^ (row & 7)) * 8)];
    }
    asm volatile("s_waitcnt lgkmcnt(0)" ::: "memory");
    __builtin_amdgcn_sched_barrier(0);
    __builtin_amdgcn_s_setprio(1);
#pragma unroll
    for (int m = 0; m < MF; ++m)
#pragma unroll
      for (int n = 0; n < NF; ++n)
        acc[m][n] = __builtin_amdgcn_mfma_f32_16x16x32_bf16(av[m], bv[n], acc[m][n], 0, 0, 0);
    __builtin_amdgcn_s_setprio(0);

    // ---- kk = 1 ----
#pragma unroll
    for (int m = 0; m < MF; ++m) {
      int row = wm * (BM / WM) + m * 16 + fr;
      av[m] = *(const bf16x8*)&sl[row * 64 + (((4 + fq) ^ (row & 7)) * 8)];
    }
#pragma unroll
    for (int n = 0; n < NF; ++n) {
      int row = wn * (BN / WN) + n * 16 + fr;
      bv[n] = *(const bf16x8*)&sl[BM * 64 + row * 64 + (((4 + fq) ^ (row & 7)) * 8)];
    }
    asm volatile("s_waitcnt lgkmcnt(0)" ::: "memory");
    __builtin_amdgcn_s_barrier();
    __builtin_amdgcn_sched_barrier(0);
    if (t + 2 < NT) stage(t + 2);
    __builtin_amdgcn_s_setprio(1);
#pragma unroll
    for (int m = 0; m < MF; ++m)
#pragma unroll
      for (int n = 0; n < NF; ++n)
        acc[m][n] = __builtin_amdgcn_mfma_f32_16x16x32_bf16(av[m], bv[n], acc[m][n], 0, 0, 0);
    __builtin_amdgcn_s_setprio(0);
  }

  // epilogue: packed Q/K write [bh][s][d]; V transposed -> Vtp[bh][d][s]
#pragma unroll
  for (int m = 0; m < MF; ++m) {
#pragma unroll
    for (int n = 0; n < NF; ++n) {
      int row0 = mBase + wm * (BM / WM) + m * 16 + fq * 4;
      int colL = wn * (BN / WN) + n * 16 + fr;
      int which = colL >> 7;
      int d = colL & 127;
      int b = row0 >> 11, s0 = row0 & (PS - 1);
      if (which == 2) {
        union { __hip_bfloat16 hh[4]; uint2 u; } pk;
#pragma unroll
        for (int j = 0; j < 4; ++j) pk.hh[j] = __float2bfloat16(acc[m][n][j]);
        *(uint2*)&Vtp[(((size_t)(b * PH + h)) * PD + d) * PS + s0] = pk.u;
      } else {
        __hip_bfloat16* dst = which == 0 ? Qp : Kp;
#pragma unroll
        for (int j = 0; j < 4; ++j)
          dst[(((size_t)(b * PH + h)) * PS + s0 + j) * PD + d] = __float2bfloat16(acc[m][n][j]);
      }
    }
  }
}

// ---------------------------------------------------------------------------
// 3-slot single-barrier GEMM (R12, validated; GEMM2).
// ---------------------------------------------------------------------------
template <int BM, int BN, int WM, int WN, typename OutT>
__global__ __launch_bounds__(512, 1) void gemm_cs3(
    const __hip_bfloat16* __restrict__ A, const __hip_bfloat16* __restrict__ Bt,
    OutT* __restrict__ C, int K, int lda, int ldb, int ldc, int nTilesX) {
  constexpr int MF = BM / WM / 16;
  constexpr int NF = BN / WN / 16;
  constexpr int SLOT = (BM + BN) * 64;
  constexpr int AL = BM / 64;
  constexpr int BL = BN / 64;
  constexpr int NLD = AL + BL;

  __shared__ __align__(16) __hip_bfloat16 lds[3 * SLOT];

  const int tid = threadIdx.x;
  const int w = tid >> 6, lane = tid & 63;
  const int fq = lane >> 4, fr = lane & 15;
  const int wm = w / WN, wn = w % WN;

  const int total = gridDim.x;
  const int swz = (blockIdx.x & 7) * (total >> 3) + (blockIdx.x >> 3);
  const int mBase = (swz / nTilesX) * BM;
  const int nBase = (swz % nTilesX) * BN;

  const int srow = tid >> 3, sc = tid & 7;

  auto stage = [&](int t) {
    char* base = (char*)lds + (size_t)(t % 3) * SLOT * 2;
#pragma unroll
    for (int l = 0; l < AL; ++l) {
      int row = l * 64 + srow;
      int cs = sc ^ (row & 7);
      gload_lds16(A + (size_t)(mBase + row) * lda + t * 64 + cs * 8,
                  base + l * 8192 + w * 1024);
    }
#pragma unroll
    for (int l = 0; l < BL; ++l) {
      int row = l * 64 + srow;
      int cs = sc ^ (row & 7);
      gload_lds16(Bt + (size_t)(nBase + row) * ldb + t * 64 + cs * 8,
                  base + BM * 128 + l * 8192 + w * 1024);
    }
  };

  f32x4 acc[MF][NF];
#pragma unroll
  for (int m = 0; m < MF; ++m)
#pragma unroll
    for (int n = 0; n < NF; ++n) acc[m][n] = (f32x4){0.f, 0.f, 0.f, 0.f};

  const int NT = K / 64;
  stage(0); stage(1);

#pragma unroll 1
  for (int t = 0; t < NT; ++t) {
    if (t + 1 < NT) asm volatile("s_waitcnt vmcnt(%0)" ::"i"(NLD) : "memory");
    else            asm volatile("s_waitcnt vmcnt(0)" ::: "memory");
    __builtin_amdgcn_s_barrier();
    __builtin_amdgcn_sched_barrier(0);
    if (t + 2 < NT) stage(t + 2);

    const __hip_bfloat16* sl = lds + (size_t)(t % 3) * SLOT;

#pragma unroll
    for (int kk = 0; kk < 2; ++kk) {
      bf16x8 av[MF], bv[NF];
#pragma unroll
      for (int m = 0; m < MF; ++m) {
        int row = wm * (BM / WM) + m * 16 + fr;
        av[m] = *(const bf16x8*)&sl[row * 64 + (((kk * 4 + fq) ^ (row & 7)) * 8)];
      }
#pragma unroll
      for (int n = 0; n < NF; ++n) {
        int row = wn * (BN / WN) + n * 16 + fr;
        bv[n] = *(const bf16x8*)&sl[BM * 64 + row * 64 + (((kk * 4 + fq) ^ (row & 7)) * 8)];
      }
      asm volatile("s_waitcnt lgkmcnt(0)" ::: "memory");
      __builtin_amdgcn_sched_barrier(0);
      __builtin_amdgcn_s_setprio(1);
#pragma unroll
      for (int m = 0; m < MF; ++m)
#pragma unroll
        for (int n = 0; n < NF; ++n)
          acc[m][n] = __builtin_amdgcn_mfma_f32_16x16x32_bf16(av[m], bv[n], acc[m][n], 0, 0, 0);
      __builtin_amdgcn_s_setprio(0);
    }
  }

#pragma unroll
  for (int m = 0; m < MF; ++m) {
#pragma unroll
    for (int n = 0; n < NF; ++n) {
      int row0 = mBase + wm * (BM / WM) + m * 16 + fq * 4;
      int col = nBase + wn * (BN / WN) + n * 16 + fr;
#pragma unroll
      for (int j = 0; j < 4; ++j) {
        if constexpr (__is_same(OutT, float))
          C[(size_t)(row0 + j) * ldc + col] = acc[m][n][j];
        else
          C[(size_t)(row0 + j) * ldc + col] = __float2bfloat16(acc[m][n][j]);
      }
    }
  }
}

// ---------------------------------------------------------------------------
__global__ __launch_bounds__(256) void transpose_cast(const float* __restrict__ W,
                                                      __hip_bfloat16* __restrict__ Wt,
                                                      int ldw, int ldt, int nOff) {
  __shared__ float t[32][33];
  int nb = blockIdx.x * 32, kb = blockIdx.y * 32;
  int tx = threadIdx.x & 31, ty = threadIdx.x >> 5;
#pragma unroll
  for (int i = 0; i < 4; ++i) {
    int k = ty + i * 8;
    t[k][tx] = W[(size_t)(kb + k) * ldw + nOff + nb + tx];
  }
  __syncthreads();
#pragma unroll
  for (int i = 0; i < 4; ++i) {
    int n = ty + i * 8;
    Wt[(size_t)(nb + n) * ldt + kb + tx] = __float2bfloat16(t[tx][n]);
  }
}

// ---------------------------------------------------------------------------
// Gate head + x cast (fused).
// ---------------------------------------------------------------------------
__global__ __launch_bounds__(256) void hg_from_x(const float* __restrict__ x,
                                                 const float* __restrict__ W,
                                                 float* __restrict__ hgbuf,
                                                 __hip_bfloat16* __restrict__ xb) {
  int bs = blockIdx.x;
  int b = bs >> 11, s = bs & (PS - 1);
  __shared__ float xs[PE];
  __shared__ float red[16][17];
  const float* xr = x + (size_t)bs * PE;
  for (int i = threadIdx.x; i < PE / 4; i += 256)
    *(float4*)&xs[i * 4] = ((const float4*)xr)[i];
  __syncthreads();
  {
    union { __hip_bfloat16 hh[8]; bf16x8 v; } pk;
#pragma unroll
    for (int k = 0; k < 8; ++k) pk.hh[k] = __float2bfloat16(xs[threadIdx.x * 8 + k]);
    *(bf16x8*)&xb[(size_t)bs * PE + threadIdx.x * 8] = pk.v;
  }
  int h = threadIdx.x & 15, part = threadIdx.x >> 4;
  float acc = 0.f;
  for (int k = part * 128; k < part * 128 + 128; ++k)
    acc += xs[k] * W[(size_t)k * PN_PROJ + 3 * PE + h];
  red[part][h] = acc;
  __syncthreads();
  if (threadIdx.x < 16) {
    float sm = 0.f;
#pragma unroll
    for (int p = 0; p < 16; ++p) sm += red[p][threadIdx.x];
    hgbuf[(size_t)(b * PH + threadIdx.x) * PS + s] = tanhf(sm);
  }
}

// ---------------------------------------------------------------------------
// Kc scan on PACKED Kp[bh][s][d] (coalesced), fp32 accum, pre-scaled by
// log2(e)/sqrt(E) — attention uses native exp2.
// ---------------------------------------------------------------------------
#define KC_SCALE 0.031879358f  // (1/sqrt(2048)) * log2(e)

__global__ __launch_bounds__(128) void kc_pass1(const __hip_bfloat16* __restrict__ Kp,
                                                const float* __restrict__ hgbuf,
                                                float* __restrict__ csum) {
  int c = blockIdx.x & 15, bh = blockIdx.x >> 4;
  int d = threadIdx.x;
  __shared__ float hgs[128];
  hgs[d] = hgbuf[(size_t)bh * PS + c * 128 + d];
  __syncthreads();
  const __hip_bfloat16* kb = Kp + ((size_t)bh * PS + c * 128) * PD + d;
  float acc = 0.f;
  int j0 = c * 128;
  for (int i = 0; i < 128; ++i)
    acc += (float)(j0 + i + 1) * hgs[i] * __bfloat162float(kb[(size_t)i * PD]);
  csum[blockIdx.x * 128 + d] = acc;
}

__global__ __launch_bounds__(128) void kc_pass2(__hip_bfloat16* __restrict__ Kp,
                                                const float* __restrict__ hgbuf,
                                                const float* __restrict__ csum) {
  int c = blockIdx.x & 15, bh = blockIdx.x >> 4;
  int d = threadIdx.x;
  __shared__ float hgs[128];
  hgs[d] = hgbuf[(size_t)bh * PS + c * 128 + d];
  __syncthreads();
  float acc = 0.f;
  for (int cc = 0; cc < c; ++cc) acc += csum[(bh * 16 + cc) * 128 + d];
  __hip_bfloat16* kb = Kp + ((size_t)bh * PS + c * 128) * PD + d;
  int j0 = c * 128;
  for (int i = 0; i < 128; ++i) {
    float t = (float)(j0 + i + 1);
    acc += t * hgs[i] * __bfloat162float(kb[(size_t)i * PD]);
    kb[(size_t)i * PD] = __float2bfloat16(acc / (t * t) * KC_SCALE);
  }
}

// ---------------------------------------------------------------------------
// MFMA flash attention v5 (R17): ONE q-tile per block, grid 512 = 2 blocks/CU
// (LDS 67.6K x2 = 135K <= 160K). LPT dispatch: qt = 15-(bid>>5) so 32-iter
// blocks launch first; bh = bid&31 -> natural XCD affinity (bh&7).
// Counted-vmcnt pipeline: per iter stage K(t+1) -> vmcnt(8) -> bar ->
// QK+softmax -> vmcnt(4) -> bar -> PV -> lgkm(0)+bar -> stage V(t+1).
// Os (34816B) overlays vbuf+Ps at epilogue.
// ---------------------------------------------------------------------------
__global__ __launch_bounds__(256) void attn_mfma(const __hip_bfloat16* __restrict__ Qp,
                                                 const __hip_bfloat16* __restrict__ Kp,
                                                 const __hip_bfloat16* __restrict__ Vtp,
                                                 __hip_bfloat16* __restrict__ O) {
  const int qt = 15 - (blockIdx.x >> 5);   // LPT: biggest blocks first
  const int bh = blockIdx.x & 31;          // same-bh blocks share XCD (bh&7)
  const int b = bh >> 4, h = bh & 15;
  const int tid = threadIdx.x;
  const int w = tid >> 6, lane = tid & 63;
  const int fq = lane >> 4, fr = lane & 15;
  const int nt = (qt + 1) * 2;
  const int q0 = qt * 128;
  const int qw = q0 + w * 32;

  __shared__ __align__(16) char smem[67584];
  __hip_bfloat16* Psw = (__hip_bfloat16*)(smem + 49152) + w * 32 * 72;
  __hip_bfloat16* Os = (__hip_bfloat16*)(smem + 32768);  // overlays vbuf+Ps

  const __hip_bfloat16* kb0 = Kp + (size_t)bh * PS * PD;
  const __hip_bfloat16* vb0 = Vtp + (size_t)bh * PD * PS;

  const int klr = lane >> 4, kc = lane & 15;
  const int vlr = lane >> 3, vc = lane & 7;

  auto stageK = [&](int t, int bufi) {
    char* ksb = smem + bufi * 16384;
    const __hip_bfloat16* kb = kb0 + (size_t)(t * 64) * PD;
#pragma unroll
    for (int p = 0; p < 4; ++p) {
      int row = w * 16 + p * 4 + klr;
      int cs = kc ^ (row & 7);
      gload_lds16(kb + (size_t)row * PD + cs * 8, ksb + (w * 16 + p * 4) * 256);
    }
  };
  auto stageV = [&](int t) {
    char* vsb = smem + 32768;
    const __hip_bfloat16* vb = vb0 + t * 64;
#pragma unroll
    for (int p = 0; p < 4; ++p) {
      int row = w * 32 + p * 8 + vlr;
      int cs = vc ^ (row & 7);
      gload_lds16(vb + (size_t)row * PS + cs * 8, vsb + (w * 32 + p * 8) * 128);
    }
  };

  // Q fragments
  const __hip_bfloat16* qbase = Qp + ((size_t)bh * PS + qw) * PD;
  bf16x8 qf[2][4];
#pragma unroll
  for (int r2 = 0; r2 < 2; ++r2)
#pragma unroll
    for (int kk = 0; kk < 4; ++kk)
      qf[r2][kk] = *(const bf16x8*)&qbase[(size_t)(r2 * 16 + fr) * PD + kk * 32 + fq * 8];

  stageK(0, 0);
  stageV(0);
  int cur = 0;

  f32x4 oacc[2][8];
#pragma unroll
  for (int r2 = 0; r2 < 2; ++r2)
#pragma unroll
    for (int nd = 0; nd < 8; ++nd) oacc[r2][nd] = (f32x4){0.f, 0.f, 0.f, 0.f};
  float m_[2] = {-__builtin_inff(), -__builtin_inff()};
  float l_[2] = {0.f, 0.f};

#pragma unroll 1
  for (int kt = 0; kt < nt; ++kt) {
    const bool hasNextK = (kt + 1 < nt);
    if (hasNextK) stageK(kt + 1, cur ^ 1);
    if (hasNextK) asm volatile("s_waitcnt vmcnt(8)" ::: "memory");
    else          asm volatile("s_waitcnt vmcnt(4)" ::: "memory");
    __builtin_amdgcn_s_barrier();       // K(t) visible to all waves
    __builtin_amdgcn_sched_barrier(0);

    const bool compute = (kt * 64 <= qw + 31);
    const bool diag = (kt * 64 + 63) > qw;
    const __hip_bfloat16* Ks = (const __hip_bfloat16*)(smem + cur * 16384);

    if (compute) {
      f32x4 sacc[2][4];
#pragma unroll
      for (int r2 = 0; r2 < 2; ++r2)
#pragma unroll
        for (int n = 0; n < 4; ++n) sacc[r2][n] = (f32x4){0.f, 0.f, 0.f, 0.f};
#pragma unroll
      for (int kk = 0; kk < 4; ++kk) {
#pragma unroll
        for (int n = 0; n < 4; ++n) {
          bf16x8 kf = *(const bf16x8*)&Ks[(n * 16 + fr) * 128 + (((kk * 4 + fq) ^ (fr & 7)) * 8)];
          sacc[0][n] = __builtin_amdgcn_mfma_f32_16x16x32_bf16(kf, qf[0][kk], sacc[0][n], 0, 0, 0);
          sacc[1][n] = __builtin_amdgcn_mfma_f32_16x16x32_bf16(kf, qf[1][kk], sacc[1][n], 0, 0, 0);
        }
      }

#pragma unroll
      for (int r2 = 0; r2 < 2; ++r2) {
        const int qg = qw + r2 * 16 + fr;
        float sv[4][4];
#pragma unroll
        for (int n = 0; n < 4; ++n)
#pragma unroll
          for (int j = 0; j < 4; ++j) {
            float s = sacc[r2][n][j];
            if (diag && (kt * 64 + n * 16 + fq * 4 + j) > qg) s = -__builtin_inff();
            sv[n][j] = s;
          }
        float pmax = sv[0][0];
#pragma unroll
        for (int n = 0; n < 4; ++n)
#pragma unroll
          for (int j = 0; j < 4; ++j) pmax = fmaxf(pmax, sv[n][j]);
        pmax = fmaxf(pmax, __shfl_xor(pmax, 16, 64));
        pmax = fmaxf(pmax, __shfl_xor(pmax, 32, 64));

        // defer-max (T13) in log2 units: 8*log2(e)
        const bool nof = __all(pmax <= m_[r2] + 11.5415605f);
        const float mn = nof ? m_[r2] : fmaxf(m_[r2], pmax);
        float ps = 0.f;
#pragma unroll
        for (int n = 0; n < 4; ++n) {
          union { __hip_bfloat16 hh[4]; uint2 u; } pkk;
#pragma unroll
          for (int j = 0; j < 4; ++j) {
            float p = exp2f(sv[n][j] - mn);
            ps += p;
            pkk.hh[j] = __float2bfloat16(p);
          }
          *(uint2*)&Psw[(r2 * 16 + fr) * 72 + n * 16 + fq * 4] = pkk.u;
        }
        ps += __shfl_xor(ps, 16, 64);
        ps += __shfl_xor(ps, 32, 64);

        if (!nof) {
          const float alpha = exp2f(m_[r2] - mn);
          l_[r2] = l_[r2] * alpha + ps;
          m_[r2] = mn;
          float a0 = __shfl(alpha, fq * 4 + 0, 64);
          float a1 = __shfl(alpha, fq * 4 + 1, 64);
          float a2 = __shfl(alpha, fq * 4 + 2, 64);
          float a3 = __shfl(alpha, fq * 4 + 3, 64);
#pragma unroll
          for (int nd = 0; nd < 8; ++nd) {
            oacc[r2][nd][0] *= a0; oacc[r2][nd][1] *= a1;
            oacc[r2][nd][2] *= a2; oacc[r2][nd][3] *= a3;
          }
        } else {
          l_[r2] += ps;
        }
      }
    }

    if (hasNextK) asm volatile("s_waitcnt vmcnt(4)" ::: "memory");
    else          asm volatile("s_waitcnt vmcnt(0)" ::: "memory");
    __builtin_amdgcn_s_barrier();       // V(t) visible to all waves
    __builtin_amdgcn_sched_barrier(0);

    if (compute) {
      const __hip_bfloat16* Vts = (const __hip_bfloat16*)(smem + 32768);
#pragma unroll
      for (int kk2 = 0; kk2 < 2; ++kk2) {
        bf16x8 pa0 = *(const bf16x8*)&Psw[(0 * 16 + fr) * 72 + kk2 * 32 + fq * 8];
        bf16x8 pa1 = *(const bf16x8*)&Psw[(1 * 16 + fr) * 72 + kk2 * 32 + fq * 8];
#pragma unroll
        for (int nd = 0; nd < 8; ++nd) {
          bf16x8 vf = *(const bf16x8*)&Vts[(nd * 16 + fr) * 64 + (((kk2 * 4 + fq) ^ (fr & 7)) * 8)];
          oacc[0][nd] = __builtin_amdgcn_mfma_f32_16x16x32_bf16(pa0, vf, oacc[0][nd], 0, 0, 0);
          oacc[1][nd] = __builtin_amdgcn_mfma_f32_16x16x32_bf16(pa1, vf, oacc[1][nd], 0, 0, 0);
        }
      }
    }

    asm volatile("s_waitcnt lgkmcnt(0)" ::: "memory");  // own LDS ops done
    __builtin_amdgcn_sched_barrier(0);
    __builtin_amdgcn_s_barrier();       // vbuf free for restaging
    if (kt + 1 < nt) stageV(kt + 1);
    cur ^= 1;
  }

  // epilogue: Os overlays vbuf+Ps (both dead; no outstanding staging)
  float i0 = 1.0f / l_[0], i1 = 1.0f / l_[1];
  float inv4[2][4];
#pragma unroll
  for (int j = 0; j < 4; ++j) {
    inv4[0][j] = __shfl(i0, fq * 4 + j, 64);
    inv4[1][j] = __shfl(i1, fq * 4 + j, 64);
  }
#pragma unroll
  for (int r2 = 0; r2 < 2; ++r2)
#pragma unroll
    for (int nd = 0; nd < 8; ++nd)
#pragma unroll
      for (int j = 0; j < 4; ++j)
        Os[(w * 32 + r2 * 16 + fq * 4 + j) * 136 + nd * 16 + fr] =
            __float2bfloat16(oacc[r2][nd][j] * inv4[r2][j]);
  __syncthreads();
#pragma unroll
  for (int it = 0; it < 8; ++it) {
    int i = it * 256 + tid;
    int row = i >> 4, ch = i & 15;
    *(bf16x8*)&O[(size_t)(b * PS + q0 + row) * PE + h * 128 + ch * 8] =
        *(const bf16x8*)&Os[row * 136 + ch * 8];
  }
}

// ---------------------------------------------------------------------------
extern "C" void kernel_launch(void* const* d_in, const int* in_sizes, int n_in,
                              void* d_out, int out_size, void* d_ws, size_t ws_size,
                              hipStream_t stream) {
  const float* x     = (const float*)d_in[0];
  const float* Wqkvh = (const float*)d_in[1];
  const float* Wout  = (const float*)d_in[2];
  float* out = (float*)d_out;

  const size_t HD = (size_t)PB * PH * PS * PD;  // 8,388,608 elems = 16.8 MB
  char* wsb = (char*)d_ws;
  __hip_bfloat16* Qp = (__hip_bfloat16*)wsb;   wsb += HD * 2;
  __hip_bfloat16* Kp = (__hip_bfloat16*)wsb;   wsb += HD * 2;
  __hip_bfloat16* Vtp = (__hip_bfloat16*)wsb;  wsb += HD * 2;
  __hip_bfloat16* xb = (__hip_bfloat16*)wsb;   wsb += (size_t)PM * PE * 2;  // also attn out
  __hip_bfloat16* Wq_t = (__hip_bfloat16*)wsb; wsb += (size_t)3 * PE * PE * 2;
  __hip_bfloat16* Wout_t = (__hip_bfloat16*)wsb; wsb += (size_t)PE * PE * 2;
  float* hgbuf = (float*)wsb;                  wsb += (size_t)PB * PH * PS * 4;
  float* csum = (float*)wsb;

  // 0) gate head + fused x->bf16 cast; weight transposes
  hg_from_x<<<PM, 256, 0, stream>>>(x, Wqkvh, hgbuf, xb);
  transpose_cast<<<dim3(3 * PE / 32, PE / 32), 256, 0, stream>>>(Wqkvh, Wq_t, PN_PROJ, PE, 0);
  transpose_cast<<<dim3(PE / 32, PE / 32), 256, 0, stream>>>(Wout, Wout_t, PE, PE, 0);

  // 1) QKV GEMM -> Qp/Kp packed + Vtp transposed; grid 512 = 2 exact rounds
  gemm_qkv<<<dim3((PM / 128) * PH), 512, 0, stream>>>(xb, Wq_t, Qp, Kp, Vtp, PE, PH);

  // 2) causal weighted cumsum on packed Kp (coalesced), pre-scaled w/ log2e
  kc_pass1<<<PB * PH * 16, 128, 0, stream>>>(Kp, hgbuf, csum);
  kc_pass2<<<PB * PH * 16, 128, 0, stream>>>(Kp, hgbuf, csum);

  // 3) MFMA flash attention v5: 512 blocks (1 q-tile each), 2 blocks/CU,
  //    LPT order (qt descending) -> xb (as O, layout (b,s,h*d))
  __hip_bfloat16* Ob = xb;
  attn_mfma<<<512, 256, 0, stream>>>(Qp, Kp, Vtp, Ob);

  // 4) out = Oattn @ W_out (fp32 out) — 3-slot single-barrier, grid 256
  gemm_cs3<128, 256, 2, 4, float>
      <<<dim3((PM / 128) * (PE / 256)), 512, 0, stream>>>(
          Ob, Wout_t, out, PE, PE, PE, PE, PE / 256);
}

// Round 18
// 322.128 us; speedup vs baseline: 1.0051x; 1.0051x over previous
//
#include <hip/hip_runtime.h>
#include <hip/hip_bf16.h>
#include <math.h>

// Problem constants: B=2, S=2048, E=2048, HEADS=16, d=128
#define PB 2
#define PS 2048
#define PE 2048
#define PH 16
#define PD 128
#define PN_PROJ 6160   // 3*E + HEADS (fp32 weight layout)
#define PM 4096        // B*S

typedef __attribute__((ext_vector_type(8))) short bf16x8;
typedef __attribute__((ext_vector_type(4))) float f32x4;

__device__ __forceinline__ void gload_lds16(const void* g, void* l) {
  __builtin_amdgcn_global_load_lds((const __attribute__((address_space(1))) void*)g,
                                   (__attribute__((address_space(3))) void*)l, 16, 0, 0);
}

// ---------------------------------------------------------------------------
// GEMM1: R9-exact cs2 schedule (proven 898 TF, 0 conflicts), 128x384 tile
// (BN=384 = exactly one head). Epilogue writes packed Qp/Kp[bh][s][d] and
// V TRANSPOSED directly into Vtp[bh][d][s].
// ---------------------------------------------------------------------------
__global__ __launch_bounds__(512, 1) void gemm_qkv(
    const __hip_bfloat16* __restrict__ A, const __hip_bfloat16* __restrict__ Bt,
    __hip_bfloat16* __restrict__ Qp, __hip_bfloat16* __restrict__ Kp,
    __hip_bfloat16* __restrict__ Vtp, int K, int nTilesX) {
  constexpr int BM = 128, BN = 384, WM = 2, WN = 4;
  constexpr int MF = BM / WM / 16;   // 4
  constexpr int NF = BN / WN / 16;   // 6
  constexpr int SLOT = (BM + BN) * 64;
  constexpr int AL = BM / 64;
  constexpr int BL = BN / 64;
  constexpr int NLD = AL + BL;

  __shared__ __align__(16) __hip_bfloat16 lds[2 * SLOT];

  const int tid = threadIdx.x;
  const int w = tid >> 6, lane = tid & 63;
  const int fq = lane >> 4, fr = lane & 15;
  const int wm = w / WN, wn = w % WN;

  const int total = gridDim.x;
  const int swz = (blockIdx.x & 7) * (total >> 3) + (blockIdx.x >> 3);
  const int mBase = (swz / nTilesX) * BM;
  const int h = swz % nTilesX;       // head (BN == 384 == one head)
  const int nBase = h * BN;

  const int srow = tid >> 3, sc = tid & 7;

  auto stage = [&](int t) {
    char* base = (char*)lds + (size_t)(t & 1) * SLOT * 2;
#pragma unroll
    for (int l = 0; l < AL; ++l) {
      int row = l * 64 + srow;
      int cs = sc ^ (row & 7);
      gload_lds16(A + (size_t)(mBase + row) * K + t * 64 + cs * 8,
                  base + l * 8192 + w * 1024);
    }
#pragma unroll
    for (int l = 0; l < BL; ++l) {
      int row = l * 64 + srow;
      int cs = sc ^ (row & 7);
      gload_lds16(Bt + (size_t)(nBase + row) * K + t * 64 + cs * 8,
                  base + BM * 128 + l * 8192 + w * 1024);
    }
  };

  f32x4 acc[MF][NF];
#pragma unroll
  for (int m = 0; m < MF; ++m)
#pragma unroll
    for (int n = 0; n < NF; ++n) acc[m][n] = (f32x4){0.f, 0.f, 0.f, 0.f};

  const int NT = K / 64;
  stage(0); stage(1);

#pragma unroll 1
  for (int t = 0; t < NT; ++t) {
    if (t + 1 < NT) asm volatile("s_waitcnt vmcnt(%0)" ::"i"(NLD) : "memory");
    else            asm volatile("s_waitcnt vmcnt(0)" ::: "memory");
    __builtin_amdgcn_s_barrier();
    __builtin_amdgcn_sched_barrier(0);

    const __hip_bfloat16* sl = lds + (size_t)(t & 1) * SLOT;

    // ---- kk = 0 ----
    bf16x8 av[MF], bv[NF];
#pragma unroll
    for (int m = 0; m < MF; ++m) {
      int row = wm * (BM / WM) + m * 16 + fr;
      av[m] = *(const bf16x8*)&sl[row * 64 + ((fq ^ (row & 7)) * 8)];
    }
#pragma unroll
    for (int n = 0; n < NF; ++n) {
      int row = wn * (BN / WN) + n * 16 + fr;
      bv[n] = *(const bf16x8*)&sl[BM * 64 + row * 64 + ((fq ^ (row & 7)) * 8)];
    }
    asm volatile("s_waitcnt lgkmcnt(0)" ::: "memory");
    __builtin_amdgcn_sched_barrier(0);
    __builtin_amdgcn_s_setprio(1);
#pragma unroll
    for (int m = 0; m < MF; ++m)
#pragma unroll
      for (int n = 0; n < NF; ++n)
        acc[m][n] = __builtin_amdgcn_mfma_f32_16x16x32_bf16(av[m], bv[n], acc[m][n], 0, 0, 0);
    __builtin_amdgcn_s_setprio(0);

    // ---- kk = 1 ----
#pragma unroll
    for (int m = 0; m < MF; ++m) {
      int row = wm * (BM / WM) + m * 16 + fr;
      av[m] = *(const bf16x8*)&sl[row * 64 + (((4 + fq) ^ (row & 7)) * 8)];
    }
#pragma unroll
    for (int n = 0; n < NF; ++n) {
      int row = wn * (BN / WN) + n * 16 + fr;
      bv[n] = *(const bf16x8*)&sl[BM * 64 + row * 64 + (((4 + fq) ^ (row & 7)) * 8)];
    }
    asm volatile("s_waitcnt lgkmcnt(0)" ::: "memory");
    __builtin_amdgcn_s_barrier();
    __builtin_amdgcn_sched_barrier(0);
    if (t + 2 < NT) stage(t + 2);
    __builtin_amdgcn_s_setprio(1);
#pragma unroll
    for (int m = 0; m < MF; ++m)
#pragma unroll
      for (int n = 0; n < NF; ++n)
        acc[m][n] = __builtin_amdgcn_mfma_f32_16x16x32_bf16(av[m], bv[n], acc[m][n], 0, 0, 0);
    __builtin_amdgcn_s_setprio(0);
  }

  // epilogue: packed Q/K write [bh][s][d]; V transposed -> Vtp[bh][d][s]
#pragma unroll
  for (int m = 0; m < MF; ++m) {
#pragma unroll
    for (int n = 0; n < NF; ++n) {
      int row0 = mBase + wm * (BM / WM) + m * 16 + fq * 4;
      int colL = wn * (BN / WN) + n * 16 + fr;
      int which = colL >> 7;
      int d = colL & 127;
      int b = row0 >> 11, s0 = row0 & (PS - 1);
      if (which == 2) {
        union { __hip_bfloat16 hh[4]; uint2 u; } pk;
#pragma unroll
        for (int j = 0; j < 4; ++j) pk.hh[j] = __float2bfloat16(acc[m][n][j]);
        *(uint2*)&Vtp[(((size_t)(b * PH + h)) * PD + d) * PS + s0] = pk.u;
      } else {
        __hip_bfloat16* dst = which == 0 ? Qp : Kp;
#pragma unroll
        for (int j = 0; j < 4; ++j)
          dst[(((size_t)(b * PH + h)) * PS + s0 + j) * PD + d] = __float2bfloat16(acc[m][n][j]);
      }
    }
  }
}

// ---------------------------------------------------------------------------
// 3-slot single-barrier GEMM (R12, validated; GEMM2).
// ---------------------------------------------------------------------------
template <int BM, int BN, int WM, int WN, typename OutT>
__global__ __launch_bounds__(512, 1) void gemm_cs3(
    const __hip_bfloat16* __restrict__ A, const __hip_bfloat16* __restrict__ Bt,
    OutT* __restrict__ C, int K, int lda, int ldb, int ldc, int nTilesX) {
  constexpr int MF = BM / WM / 16;
  constexpr int NF = BN / WN / 16;
  constexpr int SLOT = (BM + BN) * 64;
  constexpr int AL = BM / 64;
  constexpr int BL = BN / 64;
  constexpr int NLD = AL + BL;

  __shared__ __align__(16) __hip_bfloat16 lds[3 * SLOT];

  const int tid = threadIdx.x;
  const int w = tid >> 6, lane = tid & 63;
  const int fq = lane >> 4, fr = lane & 15;
  const int wm = w / WN, wn = w % WN;

  const int total = gridDim.x;
  const int swz = (blockIdx.x & 7) * (total >> 3) + (blockIdx.x >> 3);
  const int mBase = (swz / nTilesX) * BM;
  const int nBase = (swz % nTilesX) * BN;

  const int srow = tid >> 3, sc = tid & 7;

  auto stage = [&](int t) {
    char* base = (char*)lds + (size_t)(t % 3) * SLOT * 2;
#pragma unroll
    for (int l = 0; l < AL; ++l) {
      int row = l * 64 + srow;
      int cs = sc ^ (row & 7);
      gload_lds16(A + (size_t)(mBase + row) * lda + t * 64 + cs * 8,
                  base + l * 8192 + w * 1024);
    }
#pragma unroll
    for (int l = 0; l < BL; ++l) {
      int row = l * 64 + srow;
      int cs = sc ^ (row & 7);
      gload_lds16(Bt + (size_t)(nBase + row) * ldb + t * 64 + cs * 8,
                  base + BM * 128 + l * 8192 + w * 1024);
    }
  };

  f32x4 acc[MF][NF];
#pragma unroll
  for (int m = 0; m < MF; ++m)
#pragma unroll
    for (int n = 0; n < NF; ++n) acc[m][n] = (f32x4){0.f, 0.f, 0.f, 0.f};

  const int NT = K / 64;
  stage(0); stage(1);

#pragma unroll 1
  for (int t = 0; t < NT; ++t) {
    if (t + 1 < NT) asm volatile("s_waitcnt vmcnt(%0)" ::"i"(NLD) : "memory");
    else            asm volatile("s_waitcnt vmcnt(0)" ::: "memory");
    __builtin_amdgcn_s_barrier();
    __builtin_amdgcn_sched_barrier(0);
    if (t + 2 < NT) stage(t + 2);

    const __hip_bfloat16* sl = lds + (size_t)(t % 3) * SLOT;

#pragma unroll
    for (int kk = 0; kk < 2; ++kk) {
      bf16x8 av[MF], bv[NF];
#pragma unroll
      for (int m = 0; m < MF; ++m) {
        int row = wm * (BM / WM) + m * 16 + fr;
        av[m] = *(const bf16x8*)&sl[row * 64 + (((kk * 4 + fq) ^ (row & 7)) * 8)];
      }
#pragma unroll
      for (int n = 0; n < NF; ++n) {
        int row = wn * (BN / WN) + n * 16 + fr;
        bv[n] = *(const bf16x8*)&sl[BM * 64 + row * 64 + (((kk * 4 + fq) ^ (row & 7)) * 8)];
      }
      asm volatile("s_waitcnt lgkmcnt(0)" ::: "memory");
      __builtin_amdgcn_sched_barrier(0);
      __builtin_amdgcn_s_setprio(1);
#pragma unroll
      for (int m = 0; m < MF; ++m)
#pragma unroll
        for (int n = 0; n < NF; ++n)
          acc[m][n] = __builtin_amdgcn_mfma_f32_16x16x32_bf16(av[m], bv[n], acc[m][n], 0, 0, 0);
      __builtin_amdgcn_s_setprio(0);
    }
  }

#pragma unroll
  for (int m = 0; m < MF; ++m) {
#pragma unroll
    for (int n = 0; n < NF; ++n) {
      int row0 = mBase + wm * (BM / WM) + m * 16 + fq * 4;
      int col = nBase + wn * (BN / WN) + n * 16 + fr;
#pragma unroll
      for (int j = 0; j < 4; ++j) {
        if constexpr (__is_same(OutT, float))
          C[(size_t)(row0 + j) * ldc + col] = acc[m][n][j];
        else
          C[(size_t)(row0 + j) * ldc + col] = __float2bfloat16(acc[m][n][j]);
      }
    }
  }
}

// ---------------------------------------------------------------------------
__global__ __launch_bounds__(256) void transpose_cast(const float* __restrict__ W,
                                                      __hip_bfloat16* __restrict__ Wt,
                                                      int ldw, int ldt, int nOff) {
  __shared__ float t[32][33];
  int nb = blockIdx.x * 32, kb = blockIdx.y * 32;
  int tx = threadIdx.x & 31, ty = threadIdx.x >> 5;
#pragma unroll
  for (int i = 0; i < 4; ++i) {
    int k = ty + i * 8;
    t[k][tx] = W[(size_t)(kb + k) * ldw + nOff + nb + tx];
  }
  __syncthreads();
#pragma unroll
  for (int i = 0; i < 4; ++i) {
    int n = ty + i * 8;
    Wt[(size_t)(nb + n) * ldt + kb + tx] = __float2bfloat16(t[tx][n]);
  }
}

// ---------------------------------------------------------------------------
// Gate head + x cast (fused).
// ---------------------------------------------------------------------------
__global__ __launch_bounds__(256) void hg_from_x(const float* __restrict__ x,
                                                 const float* __restrict__ W,
                                                 float* __restrict__ hgbuf,
                                                 __hip_bfloat16* __restrict__ xb) {
  int bs = blockIdx.x;
  int b = bs >> 11, s = bs & (PS - 1);
  __shared__ float xs[PE];
  __shared__ float red[16][17];
  const float* xr = x + (size_t)bs * PE;
  for (int i = threadIdx.x; i < PE / 4; i += 256)
    *(float4*)&xs[i * 4] = ((const float4*)xr)[i];
  __syncthreads();
  {
    union { __hip_bfloat16 hh[8]; bf16x8 v; } pk;
#pragma unroll
    for (int k = 0; k < 8; ++k) pk.hh[k] = __float2bfloat16(xs[threadIdx.x * 8 + k]);
    *(bf16x8*)&xb[(size_t)bs * PE + threadIdx.x * 8] = pk.v;
  }
  int h = threadIdx.x & 15, part = threadIdx.x >> 4;
  float acc = 0.f;
  for (int k = part * 128; k < part * 128 + 128; ++k)
    acc += xs[k] * W[(size_t)k * PN_PROJ + 3 * PE + h];
  red[part][h] = acc;
  __syncthreads();
  if (threadIdx.x < 16) {
    float sm = 0.f;
#pragma unroll
    for (int p = 0; p < 16; ++p) sm += red[p][threadIdx.x];
    hgbuf[(size_t)(b * PH + threadIdx.x) * PS + s] = tanhf(sm);
  }
}

// ---------------------------------------------------------------------------
// Kc scan on PACKED Kp[bh][s][d] (coalesced), fp32 accum, pre-scaled by
// log2(e)/sqrt(E) — attention uses native exp2.
// ---------------------------------------------------------------------------
#define KC_SCALE 0.031879358f  // (1/sqrt(2048)) * log2(e)

__global__ __launch_bounds__(128) void kc_pass1(const __hip_bfloat16* __restrict__ Kp,
                                                const float* __restrict__ hgbuf,
                                                float* __restrict__ csum) {
  int c = blockIdx.x & 15, bh = blockIdx.x >> 4;
  int d = threadIdx.x;
  __shared__ float hgs[128];
  hgs[d] = hgbuf[(size_t)bh * PS + c * 128 + d];
  __syncthreads();
  const __hip_bfloat16* kb = Kp + ((size_t)bh * PS + c * 128) * PD + d;
  float acc = 0.f;
  int j0 = c * 128;
  for (int i = 0; i < 128; ++i)
    acc += (float)(j0 + i + 1) * hgs[i] * __bfloat162float(kb[(size_t)i * PD]);
  csum[blockIdx.x * 128 + d] = acc;
}

__global__ __launch_bounds__(128) void kc_pass2(__hip_bfloat16* __restrict__ Kp,
                                                const float* __restrict__ hgbuf,
                                                const float* __restrict__ csum) {
  int c = blockIdx.x & 15, bh = blockIdx.x >> 4;
  int d = threadIdx.x;
  __shared__ float hgs[128];
  hgs[d] = hgbuf[(size_t)bh * PS + c * 128 + d];
  __syncthreads();
  float acc = 0.f;
  for (int cc = 0; cc < c; ++cc) acc += csum[(bh * 16 + cc) * 128 + d];
  __hip_bfloat16* kb = Kp + ((size_t)bh * PS + c * 128) * PD + d;
  int j0 = c * 128;
  for (int i = 0; i < 128; ++i) {
    float t = (float)(j0 + i + 1);
    acc += t * hgs[i] * __bfloat162float(kb[(size_t)i * PD]);
    kb[(size_t)i * PD] = __float2bfloat16(acc / (t * t) * KC_SCALE);
  }
}

// ---------------------------------------------------------------------------
// MFMA flash attention v6 (R18): LDS shrunk to 58368B so 2 blocks/CU can
// co-schedule (hypothesis: usable LDS/CU < 160K; 2x58.4K = 116.7K).
// Layout: K dbuf 32K @0 | V 16K @32768 | Ps 9K @49152 (16 rows/wave —
// softmax+PV fused per row-group r2, V frags re-read per r2).
// Os (34816B) overlays @16384 at epilogue. Counted-vmcnt pipeline as v5.
// diag masking under a wave-uniform branch (only 1-2 iters hit diagonal).
// Grid 512 (1 q-tile/block), LPT order, bh=bid&31 XCD affinity.
// ---------------------------------------------------------------------------
__global__ __launch_bounds__(256) void attn_mfma(const __hip_bfloat16* __restrict__ Qp,
                                                 const __hip_bfloat16* __restrict__ Kp,
                                                 const __hip_bfloat16* __restrict__ Vtp,
                                                 __hip_bfloat16* __restrict__ O) {
  const int qt = 15 - (blockIdx.x >> 5);   // LPT: biggest blocks first
  const int bh = blockIdx.x & 31;          // same-bh blocks share XCD (bh&7)
  const int b = bh >> 4, h = bh & 15;
  const int tid = threadIdx.x;
  const int w = tid >> 6, lane = tid & 63;
  const int fq = lane >> 4, fr = lane & 15;
  const int nt = (qt + 1) * 2;
  const int q0 = qt * 128;
  const int qw = q0 + w * 32;

  __shared__ __align__(16) char smem[58368];
  __hip_bfloat16* Psw = (__hip_bfloat16*)(smem + 49152) + w * 16 * 72;  // 16 rows/wave
  __hip_bfloat16* Os = (__hip_bfloat16*)(smem + 16384);  // epilogue overlay

  const __hip_bfloat16* kb0 = Kp + (size_t)bh * PS * PD;
  const __hip_bfloat16* vb0 = Vtp + (size_t)bh * PD * PS;

  const int klr = lane >> 4, kc = lane & 15;
  const int vlr = lane >> 3, vc = lane & 7;

  auto stageK = [&](int t, int bufi) {
    char* ksb = smem + bufi * 16384;
    const __hip_bfloat16* kb = kb0 + (size_t)(t * 64) * PD;
#pragma unroll
    for (int p = 0; p < 4; ++p) {
      int row = w * 16 + p * 4 + klr;
      int cs = kc ^ (row & 7);
      gload_lds16(kb + (size_t)row * PD + cs * 8, ksb + (w * 16 + p * 4) * 256);
    }
  };
  auto stageV = [&](int t) {
    char* vsb = smem + 32768;
    const __hip_bfloat16* vb = vb0 + t * 64;
#pragma unroll
    for (int p = 0; p < 4; ++p) {
      int row = w * 32 + p * 8 + vlr;
      int cs = vc ^ (row & 7);
      gload_lds16(vb + (size_t)row * PS + cs * 8, vsb + (w * 32 + p * 8) * 128);
    }
  };

  // Q fragments
  const __hip_bfloat16* qbase = Qp + ((size_t)bh * PS + qw) * PD;
  bf16x8 qf[2][4];
#pragma unroll
  for (int r2 = 0; r2 < 2; ++r2)
#pragma unroll
    for (int kk = 0; kk < 4; ++kk)
      qf[r2][kk] = *(const bf16x8*)&qbase[(size_t)(r2 * 16 + fr) * PD + kk * 32 + fq * 8];

  stageK(0, 0);
  stageV(0);
  int cur = 0;

  f32x4 oacc[2][8];
#pragma unroll
  for (int r2 = 0; r2 < 2; ++r2)
#pragma unroll
    for (int nd = 0; nd < 8; ++nd) oacc[r2][nd] = (f32x4){0.f, 0.f, 0.f, 0.f};
  float m_[2] = {-__builtin_inff(), -__builtin_inff()};
  float l_[2] = {0.f, 0.f};

#pragma unroll 1
  for (int kt = 0; kt < nt; ++kt) {
    const bool hasNextK = (kt + 1 < nt);
    if (hasNextK) stageK(kt + 1, cur ^ 1);
    if (hasNextK) asm volatile("s_waitcnt vmcnt(8)" ::: "memory");
    else          asm volatile("s_waitcnt vmcnt(4)" ::: "memory");
    __builtin_amdgcn_s_barrier();       // K(t) visible to all waves
    __builtin_amdgcn_sched_barrier(0);

    const bool compute = (kt * 64 <= qw + 31);
    const bool diag = (kt * 64 + 63) > qw;
    const __hip_bfloat16* Ks = (const __hip_bfloat16*)(smem + cur * 16384);

    f32x4 sacc[2][4];
    if (compute) {
#pragma unroll
      for (int r2 = 0; r2 < 2; ++r2)
#pragma unroll
        for (int n = 0; n < 4; ++n) sacc[r2][n] = (f32x4){0.f, 0.f, 0.f, 0.f};
#pragma unroll
      for (int kk = 0; kk < 4; ++kk) {
#pragma unroll
        for (int n = 0; n < 4; ++n) {
          bf16x8 kf = *(const bf16x8*)&Ks[(n * 16 + fr) * 128 + (((kk * 4 + fq) ^ (fr & 7)) * 8)];
          sacc[0][n] = __builtin_amdgcn_mfma_f32_16x16x32_bf16(kf, qf[0][kk], sacc[0][n], 0, 0, 0);
          sacc[1][n] = __builtin_amdgcn_mfma_f32_16x16x32_bf16(kf, qf[1][kk], sacc[1][n], 0, 0, 0);
        }
      }
    }

    if (hasNextK) asm volatile("s_waitcnt vmcnt(4)" ::: "memory");
    else          asm volatile("s_waitcnt vmcnt(0)" ::: "memory");
    __builtin_amdgcn_s_barrier();       // V(t) visible to all waves
    __builtin_amdgcn_sched_barrier(0);

    if (compute) {
      const __hip_bfloat16* Vts = (const __hip_bfloat16*)(smem + 32768);
#pragma unroll
      for (int r2 = 0; r2 < 2; ++r2) {
        const int qg = qw + r2 * 16 + fr;
        float sv[4][4];
#pragma unroll
        for (int n = 0; n < 4; ++n)
#pragma unroll
          for (int j = 0; j < 4; ++j) sv[n][j] = sacc[r2][n][j];
        if (diag) {                     // wave-uniform branch: rare
#pragma unroll
          for (int n = 0; n < 4; ++n)
#pragma unroll
            for (int j = 0; j < 4; ++j)
              if ((kt * 64 + n * 16 + fq * 4 + j) > qg) sv[n][j] = -__builtin_inff();
        }
        float pmax = sv[0][0];
#pragma unroll
        for (int n = 0; n < 4; ++n)
#pragma unroll
          for (int j = 0; j < 4; ++j) pmax = fmaxf(pmax, sv[n][j]);
        pmax = fmaxf(pmax, __shfl_xor(pmax, 16, 64));
        pmax = fmaxf(pmax, __shfl_xor(pmax, 32, 64));

        // defer-max (T13) in log2 units: 8*log2(e)
        const bool nof = __all(pmax <= m_[r2] + 11.5415605f);
        const float mn = nof ? m_[r2] : fmaxf(m_[r2], pmax);
        float ps = 0.f;
#pragma unroll
        for (int n = 0; n < 4; ++n) {
          union { __hip_bfloat16 hh[4]; uint2 u; } pkk;
#pragma unroll
          for (int j = 0; j < 4; ++j) {
            float p = exp2f(sv[n][j] - mn);
            ps += p;
            pkk.hh[j] = __float2bfloat16(p);
          }
          *(uint2*)&Psw[fr * 72 + n * 16 + fq * 4] = pkk.u;
        }
        ps += __shfl_xor(ps, 16, 64);
        ps += __shfl_xor(ps, 32, 64);

        if (!nof) {
          const float alpha = exp2f(m_[r2] - mn);
          l_[r2] = l_[r2] * alpha + ps;
          m_[r2] = mn;
          float a0 = __shfl(alpha, fq * 4 + 0, 64);
          float a1 = __shfl(alpha, fq * 4 + 1, 64);
          float a2 = __shfl(alpha, fq * 4 + 2, 64);
          float a3 = __shfl(alpha, fq * 4 + 3, 64);
#pragma unroll
          for (int nd = 0; nd < 8; ++nd) {
            oacc[r2][nd][0] *= a0; oacc[r2][nd][1] *= a1;
            oacc[r2][nd][2] *= a2; oacc[r2][nd][3] *= a3;
          }
        } else {
          l_[r2] += ps;
        }

        // PV for this row-group (V frags re-read; Ps wave-private)
#pragma unroll
        for (int kk2 = 0; kk2 < 2; ++kk2) {
          bf16x8 pa = *(const bf16x8*)&Psw[fr * 72 + kk2 * 32 + fq * 8];
#pragma unroll
          for (int nd = 0; nd < 8; ++nd) {
            bf16x8 vf = *(const bf16x8*)&Vts[(nd * 16 + fr) * 64 + (((kk2 * 4 + fq) ^ (fr & 7)) * 8)];
            oacc[r2][nd] = __builtin_amdgcn_mfma_f32_16x16x32_bf16(pa, vf, oacc[r2][nd], 0, 0, 0);
          }
        }
      }
    }

    asm volatile("s_waitcnt lgkmcnt(0)" ::: "memory");  // own LDS ops done
    __builtin_amdgcn_sched_barrier(0);
    __builtin_amdgcn_s_barrier();       // vbuf free for restaging
    if (kt + 1 < nt) stageV(kt + 1);
    cur ^= 1;
  }

  // epilogue: Os overlays kbuf1+vbuf+Ps (all dead; no outstanding staging)
  float i0 = 1.0f / l_[0], i1 = 1.0f / l_[1];
  float inv4[2][4];
#pragma unroll
  for (int j = 0; j < 4; ++j) {
    inv4[0][j] = __shfl(i0, fq * 4 + j, 64);
    inv4[1][j] = __shfl(i1, fq * 4 + j, 64);
  }
#pragma unroll
  for (int r2 = 0; r2 < 2; ++r2)
#pragma unroll
    for (int nd = 0; nd < 8; ++nd)
#pragma unroll
      for (int j = 0; j < 4; ++j)
        Os[(w * 32 + r2 * 16 + fq * 4 + j) * 136 + nd * 16 + fr] =
            __float2bfloat16(oacc[r2][nd][j] * inv4[r2][j]);
  __syncthreads();
#pragma unroll
  for (int it = 0; it < 8; ++it) {
    int i = it * 256 + tid;
    int row = i >> 4, ch = i & 15;
    *(bf16x8*)&O[(size_t)(b * PS + q0 + row) * PE + h * 128 + ch * 8] =
        *(const bf16x8*)&Os[row * 136 + ch * 8];
  }
}

// ---------------------------------------------------------------------------
extern "C" void kernel_launch(void* const* d_in, const int* in_sizes, int n_in,
                              void* d_out, int out_size, void* d_ws, size_t ws_size,
                              hipStream_t stream) {
  const float* x     = (const float*)d_in[0];
  const float* Wqkvh = (const float*)d_in[1];
  const float* Wout  = (const float*)d_in[2];
  float* out = (float*)d_out;

  const size_t HD = (size_t)PB * PH * PS * PD;  // 8,388,608 elems = 16.8 MB
  char* wsb = (char*)d_ws;
  __hip_bfloat16* Qp = (__hip_bfloat16*)wsb;   wsb += HD * 2;
  __hip_bfloat16* Kp = (__hip_bfloat16*)wsb;   wsb += HD * 2;
  __hip_bfloat16* Vtp = (__hip_bfloat16*)wsb;  wsb += HD * 2;
  __hip_bfloat16* xb = (__hip_bfloat16*)wsb;   wsb += (size_t)PM * PE * 2;  // also attn out
  __hip_bfloat16* Wq_t = (__hip_bfloat16*)wsb; wsb += (size_t)3 * PE * PE * 2;
  __hip_bfloat16* Wout_t = (__hip_bfloat16*)wsb; wsb += (size_t)PE * PE * 2;
  float* hgbuf = (float*)wsb;                  wsb += (size_t)PB * PH * PS * 4;
  float* csum = (float*)wsb;

  // 0) gate head + fused x->bf16 cast; weight transposes
  hg_from_x<<<PM, 256, 0, stream>>>(x, Wqkvh, hgbuf, xb);
  transpose_cast<<<dim3(3 * PE / 32, PE / 32), 256, 0, stream>>>(Wqkvh, Wq_t, PN_PROJ, PE, 0);
  transpose_cast<<<dim3(PE / 32, PE / 32), 256, 0, stream>>>(Wout, Wout_t, PE, PE, 0);

  // 1) QKV GEMM -> Qp/Kp packed + Vtp transposed; grid 512 = 2 exact rounds
  gemm_qkv<<<dim3((PM / 128) * PH), 512, 0, stream>>>(xb, Wq_t, Qp, Kp, Vtp, PE, PH);

  // 2) causal weighted cumsum on packed Kp (coalesced), pre-scaled w/ log2e
  kc_pass1<<<PB * PH * 16, 128, 0, stream>>>(Kp, hgbuf, csum);
  kc_pass2<<<PB * PH * 16, 128, 0, stream>>>(Kp, hgbuf, csum);

  // 3) MFMA flash attention v6: 512 blocks, 58.4K LDS (target 2 blocks/CU),
  //    LPT order -> xb (as O, layout (b,s,h*d))
  __hip_bfloat16* Ob = xb;
  attn_mfma<<<512, 256, 0, stream>>>(Qp, Kp, Vtp, Ob);

  // 4) out = Oattn @ W_out (fp32 out) — 3-slot single-barrier, grid 256
  gemm_cs3<128, 256, 2, 4, float>
      <<<dim3((PM / 128) * (PE / 256)), 512, 0, stream>>>(
          Ob, Wout_t, out, PE, PE, PE, PE, PE / 256);
}

// Round 19
// 294.095 us; speedup vs baseline: 1.1009x; 1.0953x over previous
//
#include <hip/hip_runtime.h>
#include <hip/hip_bf16.h>
#include <math.h>

// Problem constants: B=2, S=2048, E=2048, HEADS=16, d=128
#define PB 2
#define PS 2048
#define PE 2048
#define PH 16
#define PD 128
#define PN_PROJ 6160   // 3*E + HEADS (fp32 weight layout)
#define PM 4096        // B*S

typedef __attribute__((ext_vector_type(8))) short bf16x8;
typedef __attribute__((ext_vector_type(4))) float f32x4;

__device__ __forceinline__ void gload_lds16(const void* g, void* l) {
  __builtin_amdgcn_global_load_lds((const __attribute__((address_space(1))) void*)g,
                                   (__attribute__((address_space(3))) void*)l, 16, 0, 0);
}

// ---------------------------------------------------------------------------
// GEMM1: R9-exact cs2 schedule (proven 898 TF, 0 conflicts), 128x384 tile
// (BN=384 = exactly one head). Epilogue writes packed Qp/Kp[bh][s][d] and
// V TRANSPOSED directly into Vtp[bh][d][s].
// ---------------------------------------------------------------------------
__global__ __launch_bounds__(512, 1) void gemm_qkv(
    const __hip_bfloat16* __restrict__ A, const __hip_bfloat16* __restrict__ Bt,
    __hip_bfloat16* __restrict__ Qp, __hip_bfloat16* __restrict__ Kp,
    __hip_bfloat16* __restrict__ Vtp, int K, int nTilesX) {
  constexpr int BM = 128, BN = 384, WM = 2, WN = 4;
  constexpr int MF = BM / WM / 16;   // 4
  constexpr int NF = BN / WN / 16;   // 6
  constexpr int SLOT = (BM + BN) * 64;
  constexpr int AL = BM / 64;
  constexpr int BL = BN / 64;
  constexpr int NLD = AL + BL;

  __shared__ __align__(16) __hip_bfloat16 lds[2 * SLOT];

  const int tid = threadIdx.x;
  const int w = tid >> 6, lane = tid & 63;
  const int fq = lane >> 4, fr = lane & 15;
  const int wm = w / WN, wn = w % WN;

  const int total = gridDim.x;
  const int swz = (blockIdx.x & 7) * (total >> 3) + (blockIdx.x >> 3);
  const int mBase = (swz / nTilesX) * BM;
  const int h = swz % nTilesX;       // head (BN == 384 == one head)
  const int nBase = h * BN;

  const int srow = tid >> 3, sc = tid & 7;

  auto stage = [&](int t) {
    char* base = (char*)lds + (size_t)(t & 1) * SLOT * 2;
#pragma unroll
    for (int l = 0; l < AL; ++l) {
      int row = l * 64 + srow;
      int cs = sc ^ (row & 7);
      gload_lds16(A + (size_t)(mBase + row) * K + t * 64 + cs * 8,
                  base + l * 8192 + w * 1024);
    }
#pragma unroll
    for (int l = 0; l < BL; ++l) {
      int row = l * 64 + srow;
      int cs = sc ^ (row & 7);
      gload_lds16(Bt + (size_t)(nBase + row) * K + t * 64 + cs * 8,
                  base + BM * 128 + l * 8192 + w * 1024);
    }
  };

  f32x4 acc[MF][NF];
#pragma unroll
  for (int m = 0; m < MF; ++m)
#pragma unroll
    for (int n = 0; n < NF; ++n) acc[m][n] = (f32x4){0.f, 0.f, 0.f, 0.f};

  const int NT = K / 64;
  stage(0); stage(1);

#pragma unroll 1
  for (int t = 0; t < NT; ++t) {
    if (t + 1 < NT) asm volatile("s_waitcnt vmcnt(%0)" ::"i"(NLD) : "memory");
    else            asm volatile("s_waitcnt vmcnt(0)" ::: "memory");
    __builtin_amdgcn_s_barrier();
    __builtin_amdgcn_sched_barrier(0);

    const __hip_bfloat16* sl = lds + (size_t)(t & 1) * SLOT;

    // ---- kk = 0 ----
    bf16x8 av[MF], bv[NF];
#pragma unroll
    for (int m = 0; m < MF; ++m) {
      int row = wm * (BM / WM) + m * 16 + fr;
      av[m] = *(const bf16x8*)&sl[row * 64 + ((fq ^ (row & 7)) * 8)];
    }
#pragma unroll
    for (int n = 0; n < NF; ++n) {
      int row = wn * (BN / WN) + n * 16 + fr;
      bv[n] = *(const bf16x8*)&sl[BM * 64 + row * 64 + ((fq ^ (row & 7)) * 8)];
    }
    asm volatile("s_waitcnt lgkmcnt(0)" ::: "memory");
    __builtin_amdgcn_sched_barrier(0);
    __builtin_amdgcn_s_setprio(1);
#pragma unroll
    for (int m = 0; m < MF; ++m)
#pragma unroll
      for (int n = 0; n < NF; ++n)
        acc[m][n] = __builtin_amdgcn_mfma_f32_16x16x32_bf16(av[m], bv[n], acc[m][n], 0, 0, 0);
    __builtin_amdgcn_s_setprio(0);

    // ---- kk = 1 ----
#pragma unroll
    for (int m = 0; m < MF; ++m) {
      int row = wm * (BM / WM) + m * 16 + fr;
      av[m] = *(const bf16x8*)&sl[row * 64 + (((4 + fq) ^ (row & 7)) * 8)];
    }
#pragma unroll
    for (int n = 0; n < NF; ++n) {
      int row = wn * (BN / WN) + n * 16 + fr;
      bv[n] = *(const bf16x8*)&sl[BM * 64 + row * 64 + (((4 + fq) ^ (row & 7)) * 8)];
    }
    asm volatile("s_waitcnt lgkmcnt(0)" ::: "memory");
    __builtin_amdgcn_s_barrier();
    __builtin_amdgcn_sched_barrier(0);
    if (t + 2 < NT) stage(t + 2);
    __builtin_amdgcn_s_setprio(1);
#pragma unroll
    for (int m = 0; m < MF; ++m)
#pragma unroll
      for (int n = 0; n < NF; ++n)
        acc[m][n] = __builtin_amdgcn_mfma_f32_16x16x32_bf16(av[m], bv[n], acc[m][n], 0, 0, 0);
    __builtin_amdgcn_s_setprio(0);
  }

  // epilogue: packed Q/K write [bh][s][d]; V transposed -> Vtp[bh][d][s]
#pragma unroll
  for (int m = 0; m < MF; ++m) {
#pragma unroll
    for (int n = 0; n < NF; ++n) {
      int row0 = mBase + wm * (BM / WM) + m * 16 + fq * 4;
      int colL = wn * (BN / WN) + n * 16 + fr;
      int which = colL >> 7;
      int d = colL & 127;
      int b = row0 >> 11, s0 = row0 & (PS - 1);
      if (which == 2) {
        union { __hip_bfloat16 hh[4]; uint2 u; } pk;
#pragma unroll
        for (int j = 0; j < 4; ++j) pk.hh[j] = __float2bfloat16(acc[m][n][j]);
        *(uint2*)&Vtp[(((size_t)(b * PH + h)) * PD + d) * PS + s0] = pk.u;
      } else {
        __hip_bfloat16* dst = which == 0 ? Qp : Kp;
#pragma unroll
        for (int j = 0; j < 4; ++j)
          dst[(((size_t)(b * PH + h)) * PS + s0 + j) * PD + d] = __float2bfloat16(acc[m][n][j]);
      }
    }
  }
}

// ---------------------------------------------------------------------------
// 3-slot single-barrier GEMM (R12, validated; GEMM2).
// ---------------------------------------------------------------------------
template <int BM, int BN, int WM, int WN, typename OutT>
__global__ __launch_bounds__(512, 1) void gemm_cs3(
    const __hip_bfloat16* __restrict__ A, const __hip_bfloat16* __restrict__ Bt,
    OutT* __restrict__ C, int K, int lda, int ldb, int ldc, int nTilesX) {
  constexpr int MF = BM / WM / 16;
  constexpr int NF = BN / WN / 16;
  constexpr int SLOT = (BM + BN) * 64;
  constexpr int AL = BM / 64;
  constexpr int BL = BN / 64;
  constexpr int NLD = AL + BL;

  __shared__ __align__(16) __hip_bfloat16 lds[3 * SLOT];

  const int tid = threadIdx.x;
  const int w = tid >> 6, lane = tid & 63;
  const int fq = lane >> 4, fr = lane & 15;
  const int wm = w / WN, wn = w % WN;

  const int total = gridDim.x;
  const int swz = (blockIdx.x & 7) * (total >> 3) + (blockIdx.x >> 3);
  const int mBase = (swz / nTilesX) * BM;
  const int nBase = (swz % nTilesX) * BN;

  const int srow = tid >> 3, sc = tid & 7;

  auto stage = [&](int t) {
    char* base = (char*)lds + (size_t)(t % 3) * SLOT * 2;
#pragma unroll
    for (int l = 0; l < AL; ++l) {
      int row = l * 64 + srow;
      int cs = sc ^ (row & 7);
      gload_lds16(A + (size_t)(mBase + row) * lda + t * 64 + cs * 8,
                  base + l * 8192 + w * 1024);
    }
#pragma unroll
    for (int l = 0; l < BL; ++l) {
      int row = l * 64 + srow;
      int cs = sc ^ (row & 7);
      gload_lds16(Bt + (size_t)(nBase + row) * ldb + t * 64 + cs * 8,
                  base + BM * 128 + l * 8192 + w * 1024);
    }
  };

  f32x4 acc[MF][NF];
#pragma unroll
  for (int m = 0; m < MF; ++m)
#pragma unroll
    for (int n = 0; n < NF; ++n) acc[m][n] = (f32x4){0.f, 0.f, 0.f, 0.f};

  const int NT = K / 64;
  stage(0); stage(1);

#pragma unroll 1
  for (int t = 0; t < NT; ++t) {
    if (t + 1 < NT) asm volatile("s_waitcnt vmcnt(%0)" ::"i"(NLD) : "memory");
    else            asm volatile("s_waitcnt vmcnt(0)" ::: "memory");
    __builtin_amdgcn_s_barrier();
    __builtin_amdgcn_sched_barrier(0);
    if (t + 2 < NT) stage(t + 2);

    const __hip_bfloat16* sl = lds + (size_t)(t % 3) * SLOT;

#pragma unroll
    for (int kk = 0; kk < 2; ++kk) {
      bf16x8 av[MF], bv[NF];
#pragma unroll
      for (int m = 0; m < MF; ++m) {
        int row = wm * (BM / WM) + m * 16 + fr;
        av[m] = *(const bf16x8*)&sl[row * 64 + (((kk * 4 + fq) ^ (row & 7)) * 8)];
      }
#pragma unroll
      for (int n = 0; n < NF; ++n) {
        int row = wn * (BN / WN) + n * 16 + fr;
        bv[n] = *(const bf16x8*)&sl[BM * 64 + row * 64 + (((kk * 4 + fq) ^ (row & 7)) * 8)];
      }
      asm volatile("s_waitcnt lgkmcnt(0)" ::: "memory");
      __builtin_amdgcn_sched_barrier(0);
      __builtin_amdgcn_s_setprio(1);
#pragma unroll
      for (int m = 0; m < MF; ++m)
#pragma unroll
        for (int n = 0; n < NF; ++n)
          acc[m][n] = __builtin_amdgcn_mfma_f32_16x16x32_bf16(av[m], bv[n], acc[m][n], 0, 0, 0);
      __builtin_amdgcn_s_setprio(0);
    }
  }

#pragma unroll
  for (int m = 0; m < MF; ++m) {
#pragma unroll
    for (int n = 0; n < NF; ++n) {
      int row0 = mBase + wm * (BM / WM) + m * 16 + fq * 4;
      int col = nBase + wn * (BN / WN) + n * 16 + fr;
#pragma unroll
      for (int j = 0; j < 4; ++j) {
        if constexpr (__is_same(OutT, float))
          C[(size_t)(row0 + j) * ldc + col] = acc[m][n][j];
        else
          C[(size_t)(row0 + j) * ldc + col] = __float2bfloat16(acc[m][n][j]);
      }
    }
  }
}

// ---------------------------------------------------------------------------
__global__ __launch_bounds__(256) void transpose_cast(const float* __restrict__ W,
                                                      __hip_bfloat16* __restrict__ Wt,
                                                      int ldw, int ldt, int nOff) {
  __shared__ float t[32][33];
  int nb = blockIdx.x * 32, kb = blockIdx.y * 32;
  int tx = threadIdx.x & 31, ty = threadIdx.x >> 5;
#pragma unroll
  for (int i = 0; i < 4; ++i) {
    int k = ty + i * 8;
    t[k][tx] = W[(size_t)(kb + k) * ldw + nOff + nb + tx];
  }
  __syncthreads();
#pragma unroll
  for (int i = 0; i < 4; ++i) {
    int n = ty + i * 8;
    Wt[(size_t)(nb + n) * ldt + kb + tx] = __float2bfloat16(t[tx][n]);
  }
}

// ---------------------------------------------------------------------------
// Gate head + x cast (fused).
// ---------------------------------------------------------------------------
__global__ __launch_bounds__(256) void hg_from_x(const float* __restrict__ x,
                                                 const float* __restrict__ W,
                                                 float* __restrict__ hgbuf,
                                                 __hip_bfloat16* __restrict__ xb) {
  int bs = blockIdx.x;
  int b = bs >> 11, s = bs & (PS - 1);
  __shared__ float xs[PE];
  __shared__ float red[16][17];
  const float* xr = x + (size_t)bs * PE;
  for (int i = threadIdx.x; i < PE / 4; i += 256)
    *(float4*)&xs[i * 4] = ((const float4*)xr)[i];
  __syncthreads();
  {
    union { __hip_bfloat16 hh[8]; bf16x8 v; } pk;
#pragma unroll
    for (int k = 0; k < 8; ++k) pk.hh[k] = __float2bfloat16(xs[threadIdx.x * 8 + k]);
    *(bf16x8*)&xb[(size_t)bs * PE + threadIdx.x * 8] = pk.v;
  }
  int h = threadIdx.x & 15, part = threadIdx.x >> 4;
  float acc = 0.f;
  for (int k = part * 128; k < part * 128 + 128; ++k)
    acc += xs[k] * W[(size_t)k * PN_PROJ + 3 * PE + h];
  red[part][h] = acc;
  __syncthreads();
  if (threadIdx.x < 16) {
    float sm = 0.f;
#pragma unroll
    for (int p = 0; p < 16; ++p) sm += red[p][threadIdx.x];
    hgbuf[(size_t)(b * PH + threadIdx.x) * PS + s] = tanhf(sm);
  }
}

// ---------------------------------------------------------------------------
// Kc scan on PACKED Kp[bh][s][d] (coalesced), fp32 accum, pre-scaled by
// log2(e)/sqrt(E) — attention uses native exp2.
// ---------------------------------------------------------------------------
#define KC_SCALE 0.031879358f  // (1/sqrt(2048)) * log2(e)

__global__ __launch_bounds__(128) void kc_pass1(const __hip_bfloat16* __restrict__ Kp,
                                                const float* __restrict__ hgbuf,
                                                float* __restrict__ csum) {
  int c = blockIdx.x & 15, bh = blockIdx.x >> 4;
  int d = threadIdx.x;
  __shared__ float hgs[128];
  hgs[d] = hgbuf[(size_t)bh * PS + c * 128 + d];
  __syncthreads();
  const __hip_bfloat16* kb = Kp + ((size_t)bh * PS + c * 128) * PD + d;
  float acc = 0.f;
  int j0 = c * 128;
  for (int i = 0; i < 128; ++i)
    acc += (float)(j0 + i + 1) * hgs[i] * __bfloat162float(kb[(size_t)i * PD]);
  csum[blockIdx.x * 128 + d] = acc;
}

__global__ __launch_bounds__(128) void kc_pass2(__hip_bfloat16* __restrict__ Kp,
                                                const float* __restrict__ hgbuf,
                                                const float* __restrict__ csum) {
  int c = blockIdx.x & 15, bh = blockIdx.x >> 4;
  int d = threadIdx.x;
  __shared__ float hgs[128];
  hgs[d] = hgbuf[(size_t)bh * PS + c * 128 + d];
  __syncthreads();
  float acc = 0.f;
  for (int cc = 0; cc < c; ++cc) acc += csum[(bh * 16 + cc) * 128 + d];
  __hip_bfloat16* kb = Kp + ((size_t)bh * PS + c * 128) * PD + d;
  int j0 = c * 128;
  for (int i = 0; i < 128; ++i) {
    float t = (float)(j0 + i + 1);
    acc += t * hgs[i] * __bfloat162float(kb[(size_t)i * PD]);
    kb[(size_t)i * PD] = __float2bfloat16(acc / (t * t) * KC_SCALE);
  }
}

// ---------------------------------------------------------------------------
// MFMA flash attention v7 (R19): 8-WAVE block (512 thr) on ONE 128-row
// q-tile -> 2 waves/SIMD from a single block (inter-block co-scheduling
// was refuted R16-R18). Wave w owns rows [w*16, w*16+16).
// LDS 66K: K dbuf 32K @0 | V 16K @32768 | Ps 18.4K @49152 (16 rows/wave);
// Os (34816B) overlays @16384 at epilogue.
// Counted-vmcnt (2-load units): steady top vmcnt(4), pre-PV vmcnt(2);
// tail 2/0. Grid 512, LPT order, bh=bid&31 XCD affinity.
// ---------------------------------------------------------------------------
__global__ __launch_bounds__(512, 1) void attn_mfma(const __hip_bfloat16* __restrict__ Qp,
                                                    const __hip_bfloat16* __restrict__ Kp,
                                                    const __hip_bfloat16* __restrict__ Vtp,
                                                    __hip_bfloat16* __restrict__ O) {
  const int qt = 15 - (blockIdx.x >> 5);   // LPT: biggest blocks first
  const int bh = blockIdx.x & 31;          // same-bh blocks share XCD
  const int b = bh >> 4, h = bh & 15;
  const int tid = threadIdx.x;
  const int w = tid >> 6, lane = tid & 63;
  const int fq = lane >> 4, fr = lane & 15;
  const int nt = (qt + 1) * 2;
  const int q0 = qt * 128;
  const int qw = q0 + w * 16;              // wave's 16 q-rows

  __shared__ __align__(16) char smem[67584];
  __hip_bfloat16* Psw = (__hip_bfloat16*)(smem + 49152) + w * 16 * 72;
  __hip_bfloat16* Os = (__hip_bfloat16*)(smem + 16384);  // epilogue overlay

  const __hip_bfloat16* kb0 = Kp + (size_t)bh * PS * PD;
  const __hip_bfloat16* vb0 = Vtp + (size_t)bh * PD * PS;

  auto stageK = [&](int t, int bufi) {
    char* ksb = smem + bufi * 16384;
    const __hip_bfloat16* kb = kb0 + (size_t)(t * 64) * PD;
#pragma unroll
    for (int p = 0; p < 2; ++p) {
      int s = p * 512 + tid;               // 1024 slots of 16B
      int row = s >> 4, c = s & 15;
      int cs = c ^ (row & 7);
      gload_lds16(kb + (size_t)row * PD + cs * 8,
                  ksb + (size_t)(p * 512 + (tid & ~63)) * 16);
    }
  };
  auto stageV = [&](int t) {
    char* vsb = smem + 32768;
    const __hip_bfloat16* vb = vb0 + t * 64;
#pragma unroll
    for (int p = 0; p < 2; ++p) {
      int s = p * 512 + tid;               // 1024 slots of 16B
      int row = s >> 3, c = s & 7;
      int cs = c ^ (row & 7);
      gload_lds16(vb + (size_t)row * PS + cs * 8,
                  vsb + (size_t)(p * 512 + (tid & ~63)) * 16);
    }
  };

  // Q fragments (oldest VMEM ops; covered by the first vmcnt(4))
  const __hip_bfloat16* qbase = Qp + ((size_t)bh * PS + qw) * PD;
  bf16x8 qf[4];
#pragma unroll
  for (int kk = 0; kk < 4; ++kk)
    qf[kk] = *(const bf16x8*)&qbase[(size_t)fr * PD + kk * 32 + fq * 8];

  stageK(0, 0);
  stageV(0);
  int cur = 0;

  f32x4 oacc[8];
#pragma unroll
  for (int nd = 0; nd < 8; ++nd) oacc[nd] = (f32x4){0.f, 0.f, 0.f, 0.f};
  float m_ = -__builtin_inff(), l_ = 0.f;

#pragma unroll 1
  for (int kt = 0; kt < nt; ++kt) {
    const bool hasNextK = (kt + 1 < nt);
    if (hasNextK) stageK(kt + 1, cur ^ 1);
    if (hasNextK) asm volatile("s_waitcnt vmcnt(4)" ::: "memory");
    else          asm volatile("s_waitcnt vmcnt(2)" ::: "memory");
    __builtin_amdgcn_s_barrier();       // K(t) visible to all waves
    __builtin_amdgcn_sched_barrier(0);

    const bool compute = (kt * 64 <= qw + 15);
    const bool diag = (kt * 64 + 63) > qw;
    const __hip_bfloat16* Ks = (const __hip_bfloat16*)(smem + cur * 16384);

    f32x4 sacc[4];
    if (compute) {
#pragma unroll
      for (int n = 0; n < 4; ++n) sacc[n] = (f32x4){0.f, 0.f, 0.f, 0.f};
#pragma unroll
      for (int kk = 0; kk < 4; ++kk) {
#pragma unroll
        for (int n = 0; n < 4; ++n) {
          bf16x8 kf = *(const bf16x8*)&Ks[(n * 16 + fr) * 128 + (((kk * 4 + fq) ^ (fr & 7)) * 8)];
          sacc[n] = __builtin_amdgcn_mfma_f32_16x16x32_bf16(kf, qf[kk], sacc[n], 0, 0, 0);
        }
      }
    }

    if (hasNextK) asm volatile("s_waitcnt vmcnt(2)" ::: "memory");
    else          asm volatile("s_waitcnt vmcnt(0)" ::: "memory");
    __builtin_amdgcn_s_barrier();       // V(t) visible to all waves
    __builtin_amdgcn_sched_barrier(0);

    if (compute) {
      const __hip_bfloat16* Vts = (const __hip_bfloat16*)(smem + 32768);
      const int qg = qw + fr;           // lane's q row
      float sv[4][4];
#pragma unroll
      for (int n = 0; n < 4; ++n)
#pragma unroll
        for (int j = 0; j < 4; ++j) sv[n][j] = sacc[n][j];
      if (diag) {                       // wave-uniform branch: rare
#pragma unroll
        for (int n = 0; n < 4; ++n)
#pragma unroll
          for (int j = 0; j < 4; ++j)
            if ((kt * 64 + n * 16 + fq * 4 + j) > qg) sv[n][j] = -__builtin_inff();
      }
      float pmax = sv[0][0];
#pragma unroll
      for (int n = 0; n < 4; ++n)
#pragma unroll
        for (int j = 0; j < 4; ++j) pmax = fmaxf(pmax, sv[n][j]);
      pmax = fmaxf(pmax, __shfl_xor(pmax, 16, 64));
      pmax = fmaxf(pmax, __shfl_xor(pmax, 32, 64));

      // defer-max (T13) in log2 units: 8*log2(e)
      const bool nof = __all(pmax <= m_ + 11.5415605f);
      const float mn = nof ? m_ : fmaxf(m_, pmax);
      float ps = 0.f;
#pragma unroll
      for (int n = 0; n < 4; ++n) {
        union { __hip_bfloat16 hh[4]; uint2 u; } pkk;
#pragma unroll
        for (int j = 0; j < 4; ++j) {
          float p = exp2f(sv[n][j] - mn);
          ps += p;
          pkk.hh[j] = __float2bfloat16(p);
        }
        *(uint2*)&Psw[fr * 72 + n * 16 + fq * 4] = pkk.u;
      }
      ps += __shfl_xor(ps, 16, 64);
      ps += __shfl_xor(ps, 32, 64);

      if (!nof) {
        const float alpha = exp2f(m_ - mn);
        l_ = l_ * alpha + ps;
        m_ = mn;
        float a0 = __shfl(alpha, fq * 4 + 0, 64);
        float a1 = __shfl(alpha, fq * 4 + 1, 64);
        float a2 = __shfl(alpha, fq * 4 + 2, 64);
        float a3 = __shfl(alpha, fq * 4 + 3, 64);
#pragma unroll
        for (int nd = 0; nd < 8; ++nd) {
          oacc[nd][0] *= a0; oacc[nd][1] *= a1;
          oacc[nd][2] *= a2; oacc[nd][3] *= a3;
        }
      } else {
        l_ += ps;
      }

      // PV (Ps wave-private; V frags per-wave)
#pragma unroll
      for (int kk2 = 0; kk2 < 2; ++kk2) {
        bf16x8 pa = *(const bf16x8*)&Psw[fr * 72 + kk2 * 32 + fq * 8];
#pragma unroll
        for (int nd = 0; nd < 8; ++nd) {
          bf16x8 vf = *(const bf16x8*)&Vts[(nd * 16 + fr) * 64 + (((kk2 * 4 + fq) ^ (fr & 7)) * 8)];
          oacc[nd] = __builtin_amdgcn_mfma_f32_16x16x32_bf16(pa, vf, oacc[nd], 0, 0, 0);
        }
      }
    }

    asm volatile("s_waitcnt lgkmcnt(0)" ::: "memory");  // own LDS ops done
    __builtin_amdgcn_sched_barrier(0);
    __builtin_amdgcn_s_barrier();       // vbuf free for restaging
    if (kt + 1 < nt) stageV(kt + 1);
    cur ^= 1;
  }

  // epilogue: Os overlays kbuf1+vbuf+Ps head (all dead; staging drained)
  float inv = 1.0f / l_;
  float inv4[4];
#pragma unroll
  for (int j = 0; j < 4; ++j) inv4[j] = __shfl(inv, fq * 4 + j, 64);
#pragma unroll
  for (int nd = 0; nd < 8; ++nd)
#pragma unroll
    for (int j = 0; j < 4; ++j)
      Os[(w * 16 + fq * 4 + j) * 136 + nd * 16 + fr] =
          __float2bfloat16(oacc[nd][j] * inv4[j]);
  __syncthreads();
#pragma unroll
  for (int it = 0; it < 4; ++it) {
    int i = it * 512 + tid;
    int row = i >> 4, ch = i & 15;
    *(bf16x8*)&O[(size_t)(b * PS + q0 + row) * PE + h * 128 + ch * 8] =
        *(const bf16x8*)&Os[row * 136 + ch * 8];
  }
}

// ---------------------------------------------------------------------------
extern "C" void kernel_launch(void* const* d_in, const int* in_sizes, int n_in,
                              void* d_out, int out_size, void* d_ws, size_t ws_size,
                              hipStream_t stream) {
  const float* x     = (const float*)d_in[0];
  const float* Wqkvh = (const float*)d_in[1];
  const float* Wout  = (const float*)d_in[2];
  float* out = (float*)d_out;

  const size_t HD = (size_t)PB * PH * PS * PD;  // 8,388,608 elems = 16.8 MB
  char* wsb = (char*)d_ws;
  __hip_bfloat16* Qp = (__hip_bfloat16*)wsb;   wsb += HD * 2;
  __hip_bfloat16* Kp = (__hip_bfloat16*)wsb;   wsb += HD * 2;
  __hip_bfloat16* Vtp = (__hip_bfloat16*)wsb;  wsb += HD * 2;
  __hip_bfloat16* xb = (__hip_bfloat16*)wsb;   wsb += (size_t)PM * PE * 2;  // also attn out
  __hip_bfloat16* Wq_t = (__hip_bfloat16*)wsb; wsb += (size_t)3 * PE * PE * 2;
  __hip_bfloat16* Wout_t = (__hip_bfloat16*)wsb; wsb += (size_t)PE * PE * 2;
  float* hgbuf = (float*)wsb;                  wsb += (size_t)PB * PH * PS * 4;
  float* csum = (float*)wsb;

  // 0) gate head + fused x->bf16 cast; weight transposes
  hg_from_x<<<PM, 256, 0, stream>>>(x, Wqkvh, hgbuf, xb);
  transpose_cast<<<dim3(3 * PE / 32, PE / 32), 256, 0, stream>>>(Wqkvh, Wq_t, PN_PROJ, PE, 0);
  transpose_cast<<<dim3(PE / 32, PE / 32), 256, 0, stream>>>(Wout, Wout_t, PE, PE, 0);

  // 1) QKV GEMM -> Qp/Kp packed + Vtp transposed; grid 512 = 2 exact rounds
  gemm_qkv<<<dim3((PM / 128) * PH), 512, 0, stream>>>(xb, Wq_t, Qp, Kp, Vtp, PE, PH);

  // 2) causal weighted cumsum on packed Kp (coalesced), pre-scaled w/ log2e
  kc_pass1<<<PB * PH * 16, 128, 0, stream>>>(Kp, hgbuf, csum);
  kc_pass2<<<PB * PH * 16, 128, 0, stream>>>(Kp, hgbuf, csum);

  // 3) MFMA flash attention v7: 512 blocks x 512 thr (8 waves = 2/SIMD
  //    within one block), LPT order -> xb (as O, layout (b,s,h*d))
  __hip_bfloat16* Ob = xb;
  attn_mfma<<<512, 512, 0, stream>>>(Qp, Kp, Vtp, Ob);

  // 4) out = Oattn @ W_out (fp32 out) — 3-slot single-barrier, grid 256
  gemm_cs3<128, 256, 2, 4, float>
      <<<dim3((PM / 128) * (PE / 256)), 512, 0, stream>>>(
          Ob, Wout_t, out, PE, PE, PE, PE, PE / 256);
}